// Round 3
// baseline (432.810 us; speedup 1.0000x reference)
//
#include <hip/hip_runtime.h>
#include <math.h>

#define NOBJ 8
#define NP   65536
#define NM   32
#define ND   128
// 1024 blocks = 128 per object; block = 512 points; wave = 128 points = 4 tiles of 32.

typedef __attribute__((ext_vector_type(8)))  short short8;
typedef __attribute__((ext_vector_type(16))) float f32x16;

__device__ __forceinline__ short f2bf(float f) {  // fp32 -> bf16 bits, RNE
  unsigned u = __float_as_uint(f);
  return (short)((u + 0x7FFFu + ((u >> 16) & 1u)) >> 16);
}

// sum_sq = sum_{p,m} bit * (||x_p||^2 + ||e_m||^2 - 2 x_p.e_m)
// q = x.e via mfma_f32_32x32x16_bf16:  A = X[32p x 16d], B = E^T[16d x 32m].
// A lane layout: row=lane&31, k=8*(lane>>5)+j ; B: col=lane&31, k=8*(lane>>5)+j.
// C/D: col(m)=lane&31, row(p)=(reg&3)+8*(reg>>2)+4*(lane>>5)   [verified layout]
__launch_bounds__(256, 4)
__global__ void distill_main(const float* __restrict__ net,
                             const float* __restrict__ embs,
                             const int* __restrict__ mask,
                             float* __restrict__ ws) {
  __shared__ float red[4][2];

  const int tid  = threadIdx.x;
  const int wave = tid >> 6;
  const int lane = tid & 63;
  const int row  = lane & 31;   // p-row for A loads, m for B/mask/C-col
  const int h    = lane >> 5;   // k-half
  const int o     = blockIdx.x >> 7;
  const int chunk = blockIdx.x & 127;
  const int pbase = chunk * 512 + wave * 128;   // point offset within object

  const float* X = net  + (size_t)o * NP * ND;
  const float* E = embs + (size_t)o * NM * ND;

  // ---- one-time: B fragments (all K=128 of E^T) + ||e||^2, nan-cleaned ----
  short8 Bf[8];
  float esqp = 0.f;
  const float* erow = E + (size_t)row * ND + 8 * h;
#pragma unroll
  for (int kk = 0; kk < 8; ++kk) {
    float4 e0 = *(const float4*)(erow + 16 * kk);
    float4 e1 = *(const float4*)(erow + 16 * kk + 4);
    float ev[8] = {e0.x, e0.y, e0.z, e0.w, e1.x, e1.y, e1.z, e1.w};
    short8 b;
#pragma unroll
    for (int j = 0; j < 8; ++j) {
      float v = ev[j];
      if (!isfinite(v)) v = 0.f;
      esqp += v * v;
      b[j] = f2bf(v);
    }
    Bf[kk] = b;
  }
  const float esq = esqp + __shfl_xor(esqp, 32, 64);  // full ||e_{lane&31}||^2

  // ---- X load helper: tile t, k-step kk -> 8 consecutive fp32 of this lane's row ----
  auto ldx = [&](int t, int kk, float4& a, float4& b) {
    const float* p = X + (size_t)(pbase + 32 * t + row) * ND + 8 * h + 16 * kk;
    a = *(const float4*)p;
    b = *(const float4*)(p + 4);
  };

  float4 r0[4], r1[4];                 // 4-deep ring: 4 KB in flight per wave
#pragma unroll
  for (int s = 0; s < 4; ++s) ldx(0, s, r0[s], r1[s]);

  float S = 0.f, Cnt = 0.f;
  for (int t = 0; t < 4; ++t) {
    // mask bits for this tile (in flight across the tile's MFMAs)
    const int* mrow = mask + ((size_t)o * NM + row) * NP + pbase + 32 * t + 4 * h;
    const int4 m0 = *(const int4*)(mrow);
    const int4 m1 = *(const int4*)(mrow + 8);
    const int4 m2 = *(const int4*)(mrow + 16);
    const int4 m3 = *(const int4*)(mrow + 24);

    f32x16 acc;
#pragma unroll
    for (int i = 0; i < 16; ++i) acc[i] = 0.f;
    float xsqp = 0.f;

#pragma unroll
    for (int kk = 0; kk < 8; ++kk) {
      float4 c0 = r0[kk & 3], c1 = r1[kk & 3];
      if (kk < 4)      ldx(t, kk + 4, r0[kk & 3], r1[kk & 3]);       // refill ring
      else if (t < 3)  ldx(t + 1, kk - 4, r0[kk & 3], r1[kk & 3]);   // next tile

      xsqp += c0.x * c0.x + c0.y * c0.y + c0.z * c0.z + c0.w * c0.w
            + c1.x * c1.x + c1.y * c1.y + c1.z * c1.z + c1.w * c1.w;

      short8 a;
      a[0] = f2bf(c0.x); a[1] = f2bf(c0.y); a[2] = f2bf(c0.z); a[3] = f2bf(c0.w);
      a[4] = f2bf(c1.x); a[5] = f2bf(c1.y); a[6] = f2bf(c1.z); a[7] = f2bf(c1.w);
      acc = __builtin_amdgcn_mfma_f32_32x32x16_bf16(a, Bf[kk], acc, 0, 0, 0);
    }

    const float xsq = xsqp + __shfl_xor(xsqp, 32, 64);  // lane holds xsq[row]
    const int mk[16] = {m0.x, m0.y, m0.z, m0.w, m1.x, m1.y, m1.z, m1.w,
                        m2.x, m2.y, m2.z, m2.w, m3.x, m3.y, m3.z, m3.w};
#pragma unroll
    for (int reg = 0; reg < 16; ++reg) {
      const int rowi = (reg & 3) + 8 * (reg >> 2) + 4 * h;
      const float xr = __shfl(xsq, rowi, 64);
      const float q  = acc[reg];
      const float bitf = (float)mk[reg];        // mask values are 0/1
      S   += bitf * (xr - 2.f * q);
      Cnt += bitf;
    }
  }

  float val = S + esq * Cnt;   // + sum_m cnt_m*||e_m||^2 term, per lane
  float tp  = Cnt;
#pragma unroll
  for (int off = 32; off >= 1; off >>= 1) {
    val += __shfl_xor(val, off, 64);
    tp  += __shfl_xor(tp,  off, 64);
  }
  if (lane == 0) { red[wave][0] = val; red[wave][1] = tp; }
  __syncthreads();
  if (tid == 0) {
    float a = red[0][0] + red[1][0] + red[2][0] + red[3][0];
    float b = red[0][1] + red[1][1] + red[2][1] + red[3][1];
    atomicAdd(&ws[0], a);
    atomicAdd(&ws[1], b);
  }
}

__global__ void distill_final(const float* __restrict__ ws, float* __restrict__ out) {
  float sum_sq = ws[0], tp = ws[1];
  out[0] = (tp > 0.f) ? sum_sq / ((float)ND * tp) : 0.f;
}

extern "C" void kernel_launch(void* const* d_in, const int* in_sizes, int n_in,
                              void* d_out, int out_size, void* d_ws, size_t ws_size,
                              hipStream_t stream) {
  const float* net  = (const float*)d_in[0];   // net_out [O*P, D] fp32
  const float* embs = (const float*)d_in[2];   // mask_embs [O*M, D] fp32
  const int*   mask = (const int*)d_in[3];     // mask_pts [O, M, P] int32
  float* ws = (float*)d_ws;

  hipMemsetAsync(d_ws, 0, 4 * sizeof(float), stream);
  distill_main<<<NOBJ * 128, 256, 0, stream>>>(net, embs, mask, ws);
  distill_final<<<1, 1, 0, stream>>>(ws, (float*)d_out);
}